// Round 5
// baseline (100.679 us; speedup 1.0000x reference)
//
#include <hip/hip_runtime.h>
#include <math.h>

#define BATCH 8
#define NPRED 8192
#define MPART 2048
#define NPTS  (BATCH * NPRED)      // 65536 queries
#define MTOT  (BATCH * MPART)      // 16384 partial points
#define QPL   4                    // queries per lane
#define QPB   256                  // queries per block
#define WAVES 8                    // waves per block (512 threads)
#define GPW   32                   // groups of 4 pts per wave (128 pts/split)
#define NNBLK (2 * NPTS / QPB)     // 512 blocks: (query-set, M-half) pairs
#define NCMB  (NPTS / 1024)        // 64 combine blocks (8 per batch)
#define BASE_ALPHA 0.05f
#define EPS 1e-6f

// Grouped-SoA P': group g of 4 pts -> 4 float4: {-2x}*4, {-2y}*4, {-2z}*4, {|b|^2}*4.
// Dot then is a pure 3-fma chain: d = fma(Z,az, fma(Y,ay, fma(X,ax, W))).
// near4[m] = (x,y,z,0) for single-dwordx4 nearest gathers.
__global__ __launch_bounds__(256) void prep_kernel(const float* __restrict__ partial,
                                                   float* __restrict__ ppgf,
                                                   float4* __restrict__ near4) {
    const int m = blockIdx.x * 256 + threadIdx.x;   // 64 blocks cover MTOT
    const float* p = partial + 3u * (unsigned)m;
    const float x = p[0], y = p[1], z = p[2];
    const int g = m >> 2, c = m & 3;
    float* base = ppgf + (size_t)g * 16 + c;
    base[0]  = -2.0f * x;
    base[4]  = -2.0f * y;
    base[8]  = -2.0f * z;
    base[12] = fmaf(x, x, fmaf(y, y, z * z));
    near4[m] = make_float4(x, y, z, 0.0f);
}

// Block = 512 threads = 8 waves; blockIdx = (query-set qb, M-half).
// Wave w scans its 128-pt split of this half for the 256 queries (4/lane),
// from a 16 KB LDS tile. Writes one u64 (d2,idx) key per query per half.
// FUSE: apply previous iteration's blend in the prologue (inputs from combine).
template <bool FUSE>
__global__ __launch_bounds__(512, 4) void nn_kernel(
    const float* __restrict__ src,       // [B,N,3] base positions
    const float4* __restrict__ ppg,      // [MTOT] grouped-SoA P'
    const float4* __restrict__ near4,    // [MTOT]
    const float* __restrict__ md_in,     // [NPTS]  (FUSE)
    const int*   __restrict__ idx_in,    // [NPTS]  (FUSE)
    const float* __restrict__ bmax_in,   // [NCMB]  (FUSE)
    float* __restrict__ ref_out,         // [B,N,3] (FUSE)
    unsigned long long* __restrict__ keys_out)  // [2*NPTS]
{
    __shared__ float4 tile[1024];        // 16 KB; overlaid by 8*256 u64 keys
    unsigned long long* lk = (unsigned long long*)tile;

    const int qb   = blockIdx.x >> 1;    // query set 0..255
    const int half = blockIdx.x & 1;     // M-half
    const int b    = qb >> 5;            // batch (32 query-sets per batch)
    const int tid  = threadIdx.x;
    const int wave = tid >> 6, lane = tid & 63;

    // Stage this half's 1024 pts (1024 float4), coalesced.
    const float4* gsrc = ppg + ((b << 11) + (half << 10));
    tile[tid]       = gsrc[tid];
    tile[tid + 512] = gsrc[tid + 512];

    float axq[QPL], ayq[QPL], azq[QPL], a2q[QPL];
    if (FUSE) {
        float v = bmax_in[(b << 3) + (lane & 7)];
        #pragma unroll
        for (int o = 32; o > 0; o >>= 1) v = fmaxf(v, __shfl_down(v, o, 64));
        const float maxv = __shfl(v, 0, 64);
        #pragma unroll
        for (int j = 0; j < QPL; ++j) {
            const int t = (qb << 8) + (j << 6) + lane;
            const float md = md_in[t];
            const int   id = idx_in[t];
            const float alpha = BASE_ALPHA * (2.0f - md / (maxv + EPS));
            const float4 nb = near4[(b << 11) + id];
            const float* p = src + 3u * (unsigned)t;
            const float px = p[0], py = p[1], pz = p[2];
            axq[j] = fmaf(alpha, nb.x - px, px);
            ayq[j] = fmaf(alpha, nb.y - py, py);
            azq[j] = fmaf(alpha, nb.z - pz, pz);
            if (half == 0 && wave == 0) {   // single copy of refined-1
                float* o = ref_out + 3u * (unsigned)t;
                o[0] = axq[j]; o[1] = ayq[j]; o[2] = azq[j];
            }
        }
    } else {
        #pragma unroll
        for (int j = 0; j < QPL; ++j) {
            const int t = (qb << 8) + (j << 6) + lane;
            const float* p = src + 3u * (unsigned)t;
            axq[j] = p[0]; ayq[j] = p[1]; azq[j] = p[2];
        }
    }
    #pragma unroll
    for (int j = 0; j < QPL; ++j)
        a2q[j] = fmaf(axq[j], axq[j], fmaf(ayq[j], ayq[j], azq[j] * azq[j]));

    __syncthreads();   // tile ready

    const float4* wp = tile + (wave << 7);   // this wave's 128 float4
    float best[QPL]; int bg[QPL];
    #pragma unroll
    for (int j = 0; j < QPL; ++j) { best[j] = 1e30f; bg[j] = 0; }

    // Track h = |b|^2 - 2 a.b (order-identical to d^2; a2 added later).
    #pragma unroll 4
    for (int i = 0; i < GPW; ++i) {
        const float4 X = wp[4 * i + 0];
        const float4 Y = wp[4 * i + 1];
        const float4 Z = wp[4 * i + 2];
        const float4 W = wp[4 * i + 3];
        #pragma unroll
        for (int j = 0; j < QPL; ++j) {
            const float ax = axq[j], ay = ayq[j], az = azq[j];
            const float d0 = fmaf(Z.x, az, fmaf(Y.x, ay, fmaf(X.x, ax, W.x)));
            const float d1 = fmaf(Z.y, az, fmaf(Y.y, ay, fmaf(X.y, ax, W.y)));
            const float d2 = fmaf(Z.z, az, fmaf(Y.z, ay, fmaf(X.z, ax, W.z)));
            const float d3 = fmaf(Z.w, az, fmaf(Y.w, ay, fmaf(X.w, ax, W.w)));
            const float gm = fminf(fminf(d0, d1), fminf(d2, d3));
            if (gm < best[j]) bg[j] = i;     // strict <: earliest group wins
            best[j] = fminf(best[j], gm);
        }
    }

    // Epilogue: bit-exact rescan of the winning group recovers the element.
    unsigned long long key[QPL];
    #pragma unroll
    for (int j = 0; j < QPL; ++j) {
        const int gi = bg[j];
        const float4 X = wp[4 * gi + 0];
        const float4 Y = wp[4 * gi + 1];
        const float4 Z = wp[4 * gi + 2];
        const float4 W = wp[4 * gi + 3];
        const float ax = axq[j], ay = ayq[j], az = azq[j];
        const float d0 = fmaf(Z.x, az, fmaf(Y.x, ay, fmaf(X.x, ax, W.x)));
        const float d1 = fmaf(Z.y, az, fmaf(Y.y, ay, fmaf(X.y, ax, W.y)));
        const float d2 = fmaf(Z.z, az, fmaf(Y.z, ay, fmaf(X.z, ax, W.z)));
        const float bv = best[j];
        int c;
        if      (d0 == bv) c = 0;   // fminf returns an operand exactly
        else if (d1 == bv) c = 1;
        else if (d2 == bv) c = 2;
        else               c = 3;
        const int m = (half << 10) + (wave << 7) + (gi << 2) + c; // idx in batch
        const float dd = fmaxf(bv + a2q[j], 0.0f);  // nonneg -> uint-ordered
        key[j] = ((unsigned long long)__float_as_uint(dd) << 32) | (unsigned)m;
    }

    __syncthreads();   // all tile reads done; overlay keys
    #pragma unroll
    for (int j = 0; j < QPL; ++j)
        lk[wave * QPB + (j << 6) + lane] = key[j];
    __syncthreads();

    if (wave < 4) {    // cross-split merge: u64 min == (d2, first-index) lex
        const int q2 = (wave << 6) + lane;
        unsigned long long kk = lk[q2];
        #pragma unroll
        for (int s = 1; s < WAVES; ++s) {
            const unsigned long long k = lk[s * QPB + q2];
            if (k < kk) kk = k;
        }
        keys_out[half * NPTS + (qb << 8) + q2] = kk;
    }
}

// Combine the two M-halves per query; emit md/idx and per-1024-query max.
__global__ __launch_bounds__(1024) void combine_kernel(
    const unsigned long long* __restrict__ keys,  // [2*NPTS]
    float* __restrict__ md_out, int* __restrict__ idx_out,
    float* __restrict__ bmax_out)                 // [NCMB]
{
    __shared__ float smax[16];
    const int t = blockIdx.x * 1024 + threadIdx.x;
    const int wave = threadIdx.x >> 6, lane = threadIdx.x & 63;
    const unsigned long long k0 = keys[t], k1 = keys[NPTS + t];
    const unsigned long long kk = (k1 < k0) ? k1 : k0;
    const float md = sqrtf(__uint_as_float((unsigned)(kk >> 32)));
    md_out[t]  = md;
    idx_out[t] = (int)(kk & 0xffffffffu);
    float w = md;
    #pragma unroll
    for (int o = 32; o > 0; o >>= 1) w = fmaxf(w, __shfl_down(w, o, 64));
    if (lane == 0) smax[wave] = w;
    __syncthreads();
    if (threadIdx.x < 64) {
        float v = smax[lane & 15];
        #pragma unroll
        for (int o = 32; o > 0; o >>= 1) v = fmaxf(v, __shfl_down(v, o, 64));
        if (lane == 0) bmax_out[blockIdx.x] = v;
    }
}

// Final blend: out = ref1 + alpha2*(nearest2 - ref1).
__global__ __launch_bounds__(256) void update_kernel(
    const float* __restrict__ ref1,
    const float4* __restrict__ near4,
    const float* __restrict__ md2,
    const int*   __restrict__ idx2,
    const float* __restrict__ bmax2,   // [NCMB]
    float* __restrict__ out)
{
    const int t = blockIdx.x * 256 + threadIdx.x;
    const int b = t >> 13;
    const int lane = threadIdx.x & 63;
    float v = bmax2[(b << 3) + (lane & 7)];
    #pragma unroll
    for (int o = 32; o > 0; o >>= 1) v = fmaxf(v, __shfl_down(v, o, 64));
    const float maxv = __shfl(v, 0, 64);
    const float md = md2[t];
    const int   id = idx2[t];
    const float alpha = BASE_ALPHA * (2.0f - md / (maxv + EPS));
    const float4 nb = near4[(b << 11) + id];
    const float* p = ref1 + 3u * (unsigned)t;
    const float px = p[0], py = p[1], pz = p[2];
    float* o = out + 3u * (unsigned)t;
    o[0] = fmaf(alpha, nb.x - px, px);
    o[1] = fmaf(alpha, nb.y - py, py);
    o[2] = fmaf(alpha, nb.z - pz, pz);
}

extern "C" void kernel_launch(void* const* d_in, const int* in_sizes, int n_in,
                              void* d_out, int out_size, void* d_ws, size_t ws_size,
                              hipStream_t stream) {
    const float* pred    = (const float*)d_in[0];   // [8,8192,3] fp32
    const float* partial = (const float*)d_in[1];   // [8,2048,3] fp32
    float* out = (float*)d_out;

    char* ws = (char*)d_ws;
    float4* ppg   = (float4*)ws;                        // 256 KB grouped-SoA P'
    float4* near4 = (float4*)(ws + 262144);             // 256 KB
    float*  ref1  = (float*)(ws + 524288);              // 768 KB
    float*  md1   = (float*)(ws + 1310720);             // 256 KB
    int*    idx1  = (int*)(ws + 1572864);               // 256 KB
    unsigned long long* keys = (unsigned long long*)(ws + 1835008); // 1 MB
    float*  bmax1 = (float*)(ws + 2883584);             // 256 B
    float*  bmax2 = bmax1 + NCMB;                       // 256 B

    prep_kernel<<<MTOT / 256, 256, 0, stream>>>(partial, (float*)ppg, near4);

    // Iter 1 NN (split halves) -> keys -> combine -> md1/idx1/bmax1
    nn_kernel<false><<<NNBLK, 512, 0, stream>>>(
        pred, ppg, near4, nullptr, nullptr, nullptr, nullptr, keys);
    combine_kernel<<<NCMB, 1024, 0, stream>>>(keys, md1, idx1, bmax1);

    // Iter 1 update fused into iter 2 NN (writes ref1), then combine again.
    nn_kernel<true><<<NNBLK, 512, 0, stream>>>(
        pred, ppg, near4, md1, idx1, bmax1, ref1, keys);
    combine_kernel<<<NCMB, 1024, 0, stream>>>(keys, md1, idx1, bmax2);

    // Iter 2 update: ref1 -> out
    update_kernel<<<NPTS / 256, 256, 0, stream>>>(ref1, near4, md1, idx1, bmax2, out);
}